// Round 1
// baseline (138.276 us; speedup 1.0000x reference)
//
#include <hip/hip_runtime.h>
#include <hip/hip_bf16.h>
#include <math.h>

// ---------------------------------------------------------------------------
// HierarchicalCubeMap: two cubemap mip pyramids (128-base -> 8 levels,
// 512-base -> 10 levels), per-ray trilinear sampling, exp/clip epilogue.
//
// ws layout (floats):
//   pyr1 (512 tex, levels 1..9): [0 .. 1572858)
//   pyr0 (128 tex, levels 1..7): [1572858 .. 1671156)
// ---------------------------------------------------------------------------

#define NPYR1 1572858
#define NPYR0 98298

// level offsets (floats), index = level-1
__device__ __constant__ int OFFS0[7] = {0, 73728, 92160, 96768, 97920, 98208, 98280};
__device__ __constant__ int OFFS1[9] = {0, 1179648, 1474560, 1548288, 1566720,
                                        1571328, 1572480, 1572768, 1572840};
// host copies for launch setup
static const int H_OFFS0[7] = {0, 73728, 92160, 96768, 97920, 98208, 98280};
static const int H_OFFS1[9] = {0, 1179648, 1474560, 1548288, 1566720,
                               1571328, 1572480, 1572768, 1572840};

struct PyrArgs {
    const float* src;   // source level, (6, R, R, 3)
    float* dst[5];      // up to 5 successive output levels
    int R;              // source resolution
    int tpf;            // tiles per face edge
    int T;              // tile size (min(R,32))
    int nlev;           // levels to produce
};

// Each workgroup: load one TxT source tile to LDS, emit nlev successive
// 2x2-mean levels (matches reference's recursive pairwise mean).
__global__ __launch_bounds__(256) void pyr_kernel(PyrArgs a0, PyrArgs a1, int split) {
    __shared__ float A[32 * 32 * 3];
    __shared__ float Bb[16 * 16 * 3];

    PyrArgs a = (blockIdx.x < (unsigned)split) ? a0 : a1;
    int bid = (blockIdx.x < (unsigned)split) ? blockIdx.x : blockIdx.x - split;

    const int tpf = a.tpf;
    const int face = bid / (tpf * tpf);
    const int tif = bid - face * tpf * tpf;
    const int ty = tif / tpf, tx = tif - (tif / tpf) * tpf;
    const int T = a.T, R = a.R;
    const int tid = threadIdx.x;
    const int baseY = ty * T, baseX = tx * T;

    // load tile into LDS
    const int total = T * T * 3;
    for (int idx = tid; idx < total; idx += 256) {
        int r = idx / (T * 3);
        int k = idx - r * (T * 3);
        A[r * (T * 3) + k] =
            a.src[((size_t)(face * R + baseY + r) * R + baseX) * 3 + k];
    }
    __syncthreads();

    float* cur = A;
    float* nxt = Bb;
    int curT = T;
    for (int l = 0; l < a.nlev; ++l) {
        const int nT = curT >> 1;
        const int Rg = R >> (l + 1);   // global resolution of this dst level
        const int tb = T >> (l + 1);   // tile extent at this level
        float* dst = a.dst[l];
        const int n = nT * nT * 3;
        for (int idx = tid; idx < n; idx += 256) {
            int c = idx % 3;
            int t2 = idx / 3;
            int ly = t2 / nT, lx = t2 - ly * nT;
            float s = 0.25f * (cur[((2 * ly) * curT + 2 * lx) * 3 + c] +
                               cur[((2 * ly) * curT + 2 * lx + 1) * 3 + c] +
                               cur[((2 * ly + 1) * curT + 2 * lx) * 3 + c] +
                               cur[((2 * ly + 1) * curT + 2 * lx + 1) * 3 + c]);
            nxt[(ly * nT + lx) * 3 + c] = s;
            dst[((size_t)(face * Rg + ty * tb + ly) * Rg + tx * tb + lx) * 3 + c] = s;
        }
        __syncthreads();
        float* tmp = cur; cur = nxt; nxt = tmp;
        curT = nT;
    }
}

__device__ __forceinline__ void bilin(const float* __restrict__ tex, int R,
                                      int face, float u, float v, float o[3]) {
    float xf = u * (float)R - 0.5f;
    float yf = v * (float)R - 0.5f;
    float x0f = floorf(xf), y0f = floorf(yf);
    float fx = xf - x0f, fy = yf - y0f;
    int xi = (int)x0f, yi = (int)y0f;
    int x0 = min(max(xi, 0), R - 1);
    int x1 = min(max(xi + 1, 0), R - 1);
    int y0 = min(max(yi, 0), R - 1);
    int y1 = min(max(yi + 1, 0), R - 1);
    const float* base = tex + (size_t)face * R * R * 3;
    const float* p00 = base + (y0 * R + x0) * 3;
    const float* p01 = base + (y0 * R + x1) * 3;
    const float* p10 = base + (y1 * R + x0) * 3;
    const float* p11 = base + (y1 * R + x1) * 3;
    float w00 = (1.f - fx) * (1.f - fy);
    float w01 = fx * (1.f - fy);
    float w10 = (1.f - fx) * fy;
    float w11 = fx * fy;
#pragma unroll
    for (int c = 0; c < 3; ++c)
        o[c] = w00 * p00[c] + w01 * p01[c] + w10 * p10[c] + w11 * p11[c];
}

__device__ __forceinline__ void sample_pyr(const float* __restrict__ base_tex,
                                           const float* __restrict__ pyr,
                                           const int* offs, int lmax, int R0,
                                           int face, float u, float v, float mip,
                                           float o[3]) {
    float m = fminf(fmaxf(mip, 0.f), (float)lmax);
    float l0f = floorf(m);
    int l0 = (int)l0f;
    float f = m - l0f;
    const float* t0 = (l0 == 0) ? base_tex : (pyr + offs[l0 - 1]);
    float c0[3];
    bilin(t0, R0 >> l0, face, u, v, c0);
    if (f > 0.f && l0 < lmax) {
        const float* t1 = pyr + offs[l0];  // level l0+1
        float c1[3];
        bilin(t1, R0 >> (l0 + 1), face, u, v, c1);
        float w0 = 1.f - f;
#pragma unroll
        for (int c = 0; c < 3; ++c) o[c] = w0 * c0[c] + f * c1[c];
    } else {
#pragma unroll
        for (int c = 0; c < 3; ++c) o[c] = c0[c];
    }
}

__global__ __launch_bounds__(256) void sample_kernel(
    const float* __restrict__ vd, const float* __restrict__ sa,
    const float* __restrict__ nu, const float* __restrict__ tex0,
    const float* __restrict__ tex1, const float* __restrict__ sb,
    const float* __restrict__ sm, const float* __restrict__ smb,
    const float* __restrict__ pyr0, const float* __restrict__ pyr1,
    float* __restrict__ out, int n) {
    int i = blockIdx.x * 256 + threadIdx.x;
    if (i >= n) return;

    float x = vd[3 * i + 0];
    float y = vd[3 * i + 1];
    float z = vd[3 * i + 2];
    float ax = fabsf(x), ay = fabsf(y), az = fabsf(z);

    bool is_x = (ax >= ay) && (ax >= az);
    bool is_y = (!is_x) && (ay >= az);

    int face;
    float ma, sc, tc;
    if (is_x) {
        face = (x >= 0.f) ? 0 : 1;
        ma = ax;
        sc = (x >= 0.f) ? -z : z;
        tc = -y;
    } else if (is_y) {
        face = (y >= 0.f) ? 2 : 3;
        ma = ay;
        sc = x;
        tc = (y >= 0.f) ? z : -z;
    } else {
        face = (z >= 0.f) ? 4 : 5;
        ma = az;
        sc = (z >= 0.f) ? x : -x;
        tc = -y;
    }
    float u = 0.5f * (sc / ma + 1.f);
    float t = 0.5f * (tc / ma + 1.f);

    // miplevel
    float distortion = 1.f / ma;               // 1 / max|v|
    float saTexel = distortion / 512.f / 512.f;
    float mip = (sa[i] - logf(saTexel)) / 1.3862943611198906f / 2.0f +
                smb[0] + 0.5f * nu[i];
    mip = fmaxf(mip, 0.f);

    float s0[3], s1[3];
    sample_pyr(tex0, pyr0, OFFS0, 7, 128, face, u, t, mip, s0);
    sample_pyr(tex1, pyr1, OFFS1, 9, 512, face, u, t, mip, s1);

    float b = fminf(fmaxf(sb[0], -1.f), 2.f);
    float mul = sm[0];
#pragma unroll
    for (int c = 0; c < 3; ++c) {
        float e = expf(b + mul * (s0[c] + s1[c]));
        out[3 * i + c] = fminf(fmaxf(e, 0.01f), 1000.f);
    }
}

extern "C" void kernel_launch(void* const* d_in, const int* in_sizes, int n_in,
                              void* d_out, int out_size, void* d_ws, size_t ws_size,
                              hipStream_t stream) {
    const float* vd = (const float*)d_in[0];
    const float* sa = (const float*)d_in[1];
    const float* nu = (const float*)d_in[2];
    const float* tex0 = (const float*)d_in[3];  // (6,128,128,3)
    const float* tex1 = (const float*)d_in[4];  // (6,512,512,3)
    const float* br = (const float*)d_in[5];
    const float* mu = (const float*)d_in[6];
    const float* mb = (const float*)d_in[7];
    float* out = (float*)d_out;

    float* pyr1 = (float*)d_ws;
    float* pyr0 = pyr1 + NPYR1;

    const int B = in_sizes[1];

    // --- pyramid build, launch 1: big levels ---
    PyrArgs a0{}, a1{};
    a0.src = tex1; a0.R = 512; a0.tpf = 16; a0.T = 32; a0.nlev = 5;
    for (int l = 0; l < 5; ++l) a0.dst[l] = pyr1 + H_OFFS1[l];
    a1.src = tex0; a1.R = 128; a1.tpf = 4; a1.T = 32; a1.nlev = 5;
    for (int l = 0; l < 5; ++l) a1.dst[l] = pyr0 + H_OFFS0[l];
    int split1 = 6 * 16 * 16;                 // 1536 tex1 tiles
    int grid1 = split1 + 6 * 4 * 4;           // + 96 tex0 tiles
    hipLaunchKernelGGL(pyr_kernel, dim3(grid1), dim3(256), 0, stream, a0, a1, split1);

    // --- pyramid build, launch 2: tails ---
    PyrArgs b0{}, b1{};
    b0.src = pyr1 + H_OFFS1[4]; b0.R = 16; b0.tpf = 1; b0.T = 16; b0.nlev = 4;
    for (int l = 0; l < 4; ++l) b0.dst[l] = pyr1 + H_OFFS1[5 + l];
    b1.src = pyr0 + H_OFFS0[4]; b1.R = 4; b1.tpf = 1; b1.T = 4; b1.nlev = 2;
    for (int l = 0; l < 2; ++l) b1.dst[l] = pyr0 + H_OFFS0[5 + l];
    hipLaunchKernelGGL(pyr_kernel, dim3(12), dim3(256), 0, stream, b0, b1, 6);

    // --- sampling ---
    int grid = (B + 255) / 256;
    hipLaunchKernelGGL(sample_kernel, dim3(grid), dim3(256), 0, stream,
                       vd, sa, nu, tex0, tex1, br, mu, mb, pyr0, pyr1, out, B);
}

// Round 2
// 137.409 us; speedup vs baseline: 1.0063x; 1.0063x over previous
//
#include <hip/hip_runtime.h>
#include <hip/hip_bf16.h>
#include <math.h>

// ---------------------------------------------------------------------------
// HierarchicalCubeMap, round 2: RGBA (float4) pyramid layout so every
// bilinear tap is a single global_load_dwordx4 (48 -> 16 loads per ray).
//
// ws layout (float4 units):
//   pyr1 (512 base, levels 1..9): [0 .. 524286)
//   pyr0 (128 base, levels 1..7): [524286 .. 557052)
// ---------------------------------------------------------------------------

#define NPYR1_4 524286

// level offsets in float4 units, index = level-1
__device__ __constant__ int OFFS0[7] = {0, 24576, 30720, 32256, 32640, 32736, 32760};
__device__ __constant__ int OFFS1[9] = {0, 393216, 491520, 516096, 522240,
                                        523776, 524160, 524256, 524280};
static const int H_OFFS0[7] = {0, 24576, 30720, 32256, 32640, 32736, 32760};
static const int H_OFFS1[9] = {0, 393216, 491520, 516096, 522240,
                               523776, 524160, 524256, 524280};

struct PyrArgs {
    const void* src;    // source level: RGB float3 (rgba=0) or float4 (rgba=1)
    float4* dst[5];     // up to 5 successive output levels (RGBA)
    int R;              // source resolution
    int tpf;            // tiles per face edge
    int T;              // tile size
    int nlev;           // levels to produce
    int rgba;           // src layout flag
};

// Each workgroup: load one TxT source tile to LDS (as float4), emit nlev
// successive 2x2-mean levels (matches reference's recursive pairwise mean).
__global__ __launch_bounds__(256) void pyr_kernel(PyrArgs a0, PyrArgs a1, int split) {
    __shared__ float4 A[32 * 32];
    __shared__ float4 Bb[16 * 16];

    PyrArgs a = (blockIdx.x < (unsigned)split) ? a0 : a1;
    int bid = (blockIdx.x < (unsigned)split) ? blockIdx.x : blockIdx.x - split;

    const int tpf = a.tpf;
    const int face = bid / (tpf * tpf);
    const int tif = bid - face * tpf * tpf;
    const int ty = tif / tpf, tx = tif - (tif / tpf) * tpf;
    const int T = a.T, R = a.R;
    const int tid = threadIdx.x;
    const int baseY = ty * T, baseX = tx * T;

    // load tile into LDS as float4
    const int total = T * T;
    if (a.rgba) {
        const float4* src = (const float4*)a.src;
        for (int idx = tid; idx < total; idx += 256) {
            int r = idx / T, c = idx - (idx / T) * T;
            A[r * T + c] = src[(size_t)(face * R + baseY + r) * R + baseX + c];
        }
    } else {
        const float* src = (const float*)a.src;
        for (int idx = tid; idx < total; idx += 256) {
            int r = idx / T, c = idx - (idx / T) * T;
            const float* p = src + ((size_t)(face * R + baseY + r) * R + baseX + c) * 3;
            A[r * T + c] = make_float4(p[0], p[1], p[2], 0.f);
        }
    }
    __syncthreads();

    float4* cur = A;
    float4* nxt = Bb;
    int curT = T;
    for (int l = 0; l < a.nlev; ++l) {
        const int nT = curT >> 1;
        const int Rg = R >> (l + 1);   // global resolution of this dst level
        const int tb = T >> (l + 1);   // tile extent at this level
        float4* dst = a.dst[l];
        const int n = nT * nT;
        for (int idx = tid; idx < n; idx += 256) {
            int ly = idx / nT, lx = idx - (idx / nT) * nT;
            float4 q00 = cur[(2 * ly) * curT + 2 * lx];
            float4 q01 = cur[(2 * ly) * curT + 2 * lx + 1];
            float4 q10 = cur[(2 * ly + 1) * curT + 2 * lx];
            float4 q11 = cur[(2 * ly + 1) * curT + 2 * lx + 1];
            float4 s = make_float4(0.25f * (q00.x + q01.x + q10.x + q11.x),
                                   0.25f * (q00.y + q01.y + q10.y + q11.y),
                                   0.25f * (q00.z + q01.z + q10.z + q11.z), 0.f);
            nxt[ly * nT + lx] = s;
            dst[(size_t)(face * Rg + ty * tb + ly) * Rg + tx * tb + lx] = s;
        }
        __syncthreads();
        float4* tmp = cur; cur = nxt; nxt = tmp;
        curT = nT;
    }
}

// bilinear tap from RGBA level: 4x global_load_dwordx4
__device__ __forceinline__ void bilin4(const float4* __restrict__ tex, int R,
                                       int face, float u, float v, float o[3]) {
    float xf = u * (float)R - 0.5f;
    float yf = v * (float)R - 0.5f;
    float x0f = floorf(xf), y0f = floorf(yf);
    float fx = xf - x0f, fy = yf - y0f;
    int xi = (int)x0f, yi = (int)y0f;
    int x0 = min(max(xi, 0), R - 1);
    int x1 = min(max(xi + 1, 0), R - 1);
    int y0 = min(max(yi, 0), R - 1);
    int y1 = min(max(yi + 1, 0), R - 1);
    const float4* base = tex + (size_t)face * R * R;
    float4 p00 = base[y0 * R + x0];
    float4 p01 = base[y0 * R + x1];
    float4 p10 = base[y1 * R + x0];
    float4 p11 = base[y1 * R + x1];
    float w00 = (1.f - fx) * (1.f - fy);
    float w01 = fx * (1.f - fy);
    float w10 = (1.f - fx) * fy;
    float w11 = fx * fy;
    o[0] = w00 * p00.x + w01 * p01.x + w10 * p10.x + w11 * p11.x;
    o[1] = w00 * p00.y + w01 * p01.y + w10 * p10.y + w11 * p11.y;
    o[2] = w00 * p00.z + w01 * p01.z + w10 * p10.z + w11 * p11.z;
}

// bilinear tap from the RGB base texture (level 0 fallback — mip<1 is rare)
__device__ __forceinline__ void bilin3(const float* __restrict__ tex, int R,
                                       int face, float u, float v, float o[3]) {
    float xf = u * (float)R - 0.5f;
    float yf = v * (float)R - 0.5f;
    float x0f = floorf(xf), y0f = floorf(yf);
    float fx = xf - x0f, fy = yf - y0f;
    int xi = (int)x0f, yi = (int)y0f;
    int x0 = min(max(xi, 0), R - 1);
    int x1 = min(max(xi + 1, 0), R - 1);
    int y0 = min(max(yi, 0), R - 1);
    int y1 = min(max(yi + 1, 0), R - 1);
    const float* base = tex + (size_t)face * R * R * 3;
    const float* p00 = base + (y0 * R + x0) * 3;
    const float* p01 = base + (y0 * R + x1) * 3;
    const float* p10 = base + (y1 * R + x0) * 3;
    const float* p11 = base + (y1 * R + x1) * 3;
    float w00 = (1.f - fx) * (1.f - fy);
    float w01 = fx * (1.f - fy);
    float w10 = (1.f - fx) * fy;
    float w11 = fx * fy;
#pragma unroll
    for (int c = 0; c < 3; ++c)
        o[c] = w00 * p00[c] + w01 * p01[c] + w10 * p10[c] + w11 * p11[c];
}

__device__ __forceinline__ void sample_pyr(const float* __restrict__ base_tex,
                                           const float4* __restrict__ pyr,
                                           const int* offs, int lmax, int R0,
                                           int face, float u, float v, float mip,
                                           float o[3]) {
    float m = fminf(fmaxf(mip, 0.f), (float)lmax);
    float l0f = floorf(m);
    int l0 = (int)l0f;
    float f = m - l0f;
    float c0[3];
    if (l0 == 0)
        bilin3(base_tex, R0, face, u, v, c0);
    else
        bilin4(pyr + offs[l0 - 1], R0 >> l0, face, u, v, c0);
    if (f > 0.f && l0 < lmax) {
        float c1[3];
        bilin4(pyr + offs[l0], R0 >> (l0 + 1), face, u, v, c1);
        float w0 = 1.f - f;
#pragma unroll
        for (int c = 0; c < 3; ++c) o[c] = w0 * c0[c] + f * c1[c];
    } else {
#pragma unroll
        for (int c = 0; c < 3; ++c) o[c] = c0[c];
    }
}

__global__ __launch_bounds__(256) void sample_kernel(
    const float* __restrict__ vd, const float* __restrict__ sa,
    const float* __restrict__ nu, const float* __restrict__ tex0,
    const float* __restrict__ tex1, const float* __restrict__ sb,
    const float* __restrict__ sm, const float* __restrict__ smb,
    const float4* __restrict__ pyr0, const float4* __restrict__ pyr1,
    float* __restrict__ out, int n) {
    int i = blockIdx.x * 256 + threadIdx.x;
    if (i >= n) return;

    float x = vd[3 * i + 0];
    float y = vd[3 * i + 1];
    float z = vd[3 * i + 2];
    float ax = fabsf(x), ay = fabsf(y), az = fabsf(z);

    bool is_x = (ax >= ay) && (ax >= az);
    bool is_y = (!is_x) && (ay >= az);

    int face;
    float ma, sc, tc;
    if (is_x) {
        face = (x >= 0.f) ? 0 : 1;
        ma = ax;
        sc = (x >= 0.f) ? -z : z;
        tc = -y;
    } else if (is_y) {
        face = (y >= 0.f) ? 2 : 3;
        ma = ay;
        sc = x;
        tc = (y >= 0.f) ? z : -z;
    } else {
        face = (z >= 0.f) ? 4 : 5;
        ma = az;
        sc = (z >= 0.f) ? x : -x;
        tc = -y;
    }
    float u = 0.5f * (sc / ma + 1.f);
    float t = 0.5f * (tc / ma + 1.f);

    // miplevel
    float distortion = 1.f / ma;
    float saTexel = distortion / 512.f / 512.f;
    float mip = (sa[i] - logf(saTexel)) / 1.3862943611198906f / 2.0f +
                smb[0] + 0.5f * nu[i];
    mip = fmaxf(mip, 0.f);

    float s0[3], s1[3];
    sample_pyr(tex0, pyr0, OFFS0, 7, 128, face, u, t, mip, s0);
    sample_pyr(tex1, pyr1, OFFS1, 9, 512, face, u, t, mip, s1);

    float b = fminf(fmaxf(sb[0], -1.f), 2.f);
    float mul = sm[0];
#pragma unroll
    for (int c = 0; c < 3; ++c) {
        float e = expf(b + mul * (s0[c] + s1[c]));
        out[3 * i + c] = fminf(fmaxf(e, 0.01f), 1000.f);
    }
}

extern "C" void kernel_launch(void* const* d_in, const int* in_sizes, int n_in,
                              void* d_out, int out_size, void* d_ws, size_t ws_size,
                              hipStream_t stream) {
    const float* vd = (const float*)d_in[0];
    const float* sa = (const float*)d_in[1];
    const float* nu = (const float*)d_in[2];
    const float* tex0 = (const float*)d_in[3];  // (6,128,128,3)
    const float* tex1 = (const float*)d_in[4];  // (6,512,512,3)
    const float* br = (const float*)d_in[5];
    const float* mu = (const float*)d_in[6];
    const float* mb = (const float*)d_in[7];
    float* out = (float*)d_out;

    float4* pyr1 = (float4*)d_ws;
    float4* pyr0 = pyr1 + NPYR1_4;

    const int B = in_sizes[1];

    // --- pyramid build, launch 1: big levels (1..5 of each) ---
    PyrArgs a0{}, a1{};
    a0.src = tex1; a0.R = 512; a0.tpf = 16; a0.T = 32; a0.nlev = 5; a0.rgba = 0;
    for (int l = 0; l < 5; ++l) a0.dst[l] = pyr1 + H_OFFS1[l];
    a1.src = tex0; a1.R = 128; a1.tpf = 4; a1.T = 32; a1.nlev = 5; a1.rgba = 0;
    for (int l = 0; l < 5; ++l) a1.dst[l] = pyr0 + H_OFFS0[l];
    int split1 = 6 * 16 * 16;
    int grid1 = split1 + 6 * 4 * 4;
    hipLaunchKernelGGL(pyr_kernel, dim3(grid1), dim3(256), 0, stream, a0, a1, split1);

    // --- pyramid build, launch 2: tails ---
    PyrArgs b0{}, b1{};
    b0.src = pyr1 + H_OFFS1[4]; b0.R = 16; b0.tpf = 1; b0.T = 16; b0.nlev = 4; b0.rgba = 1;
    for (int l = 0; l < 4; ++l) b0.dst[l] = pyr1 + H_OFFS1[5 + l];
    b1.src = pyr0 + H_OFFS0[4]; b1.R = 4; b1.tpf = 1; b1.T = 4; b1.nlev = 2; b1.rgba = 1;
    for (int l = 0; l < 2; ++l) b1.dst[l] = pyr0 + H_OFFS0[5 + l];
    hipLaunchKernelGGL(pyr_kernel, dim3(12), dim3(256), 0, stream, b0, b1, 6);

    // --- sampling ---
    int grid = (B + 255) / 256;
    hipLaunchKernelGGL(sample_kernel, dim3(grid), dim3(256), 0, stream,
                       vd, sa, nu, tex0, tex1, br, mu, mb, pyr0, pyr1, out, B);
}